// Round 1
// baseline (159.275 us; speedup 1.0000x reference)
//
#include <hip/hip_runtime.h>
#include <cstdint>

#define CIN 96
#define DIN 96
#define DTR 8
#define DST 16
#define HH 128
#define WW 128
#define HW (HH*WW)
#define NPIX (2*HW)   // B=2

// ---------------- Stage 1: per-pixel matvecs -> delta, B, C, xh ----------------
__global__ __launch_bounds__(256) void ssm2d_stage1(
    const float* __restrict__ x,
    const float* __restrict__ W1, const float* __restrict__ b1,
    const float* __restrict__ dtw, const float* __restrict__ dtb,
    const float* __restrict__ alog,
    float* __restrict__ dws, float* __restrict__ xws,
    float* __restrict__ Bws, float* __restrict__ Cws,
    float* __restrict__ Aws)
{
    // block 0 additionally materializes A = -exp(A_log) (1536 floats)
    if (blockIdx.x == 0) {
        for (int i = threadIdx.x; i < DIN * DST; i += blockDim.x)
            Aws[i] = -__expf(alog[i]);
    }

    int p = blockIdx.x * blockDim.x + threadIdx.x;   // global pixel id (b*HW + r*W + c)
    if (p >= NPIX) return;
    int b = p >> 14;            // HW = 16384
    int q = p & (HW - 1);
    const float* xb = x + ((size_t)b * CIN) * HW + q;   // x[b, ch, r, c], stride HW over ch

    float acc[40];
    #pragma unroll
    for (int o = 0; o < 40; ++o) acc[o] = b1[o];

    for (int ch = 0; ch < CIN; ch += 4) {
        float xv0 = xb[(ch + 0) * HW];
        float xv1 = xb[(ch + 1) * HW];
        float xv2 = xb[(ch + 2) * HW];
        float xv3 = xb[(ch + 3) * HW];
        xws[p * DIN + ch + 0] = xv0;
        xws[p * DIN + ch + 1] = xv1;
        xws[p * DIN + ch + 2] = xv2;
        xws[p * DIN + ch + 3] = xv3;
        #pragma unroll
        for (int o = 0; o < 40; ++o) {
            const float4 w = *reinterpret_cast<const float4*>(W1 + o * CIN + ch);
            acc[o] = fmaf(xv0, w.x, acc[o]);
            acc[o] = fmaf(xv1, w.y, acc[o]);
            acc[o] = fmaf(xv2, w.z, acc[o]);
            acc[o] = fmaf(xv3, w.w, acc[o]);
        }
    }

    // B = dBC[8:24], C = dBC[24:40]
    #pragma unroll
    for (int n = 0; n < DST; ++n) {
        Bws[p * DST + n] = acc[DTR + n];
        Cws[p * DST + n] = acc[DTR + DST + n];
    }

    // delta = softplus(dt_w @ dBC[0:8] + dt_b)
    for (int d = 0; d < DIN; ++d) {
        float t = dtb[d];
        #pragma unroll
        for (int k = 0; k < DTR; ++k) t = fmaf(acc[k], dtw[d * DTR + k], t);
        float sp = (t > 20.0f) ? t : log1pf(__expf(t));
        dws[p * DIN + d] = sp;
    }
}

// ---------------- Stage 2: diagonal-chain scan + output contraction ----------------
__global__ __launch_bounds__(256) void ssm2d_stage2(
    const float* __restrict__ dws, const float* __restrict__ xws,
    const float* __restrict__ Bws, const float* __restrict__ Cws,
    const float* __restrict__ Aws, const float* __restrict__ Dv,
    float* __restrict__ out)
{
    int i = blockIdx.x * blockDim.x + threadIdx.x;  // i = p*96 + d
    if (i >= NPIX * DIN) return;
    int p = i / DIN;
    int d = i - p * DIN;
    int q = p & (HW - 1);
    int r = q >> 7;         // WW = 128
    int c = q & (WW - 1);

    int m = __builtin_ctz(r + 1);
    int mc = __builtin_ctz(c + 1);
    if (mc < m) m = mc;           // m <= 7 automatically (r+1, c+1 <= 128)
    int L = 1 << m;

    float delta0 = dws[i];
    float x0 = xws[i];
    float coef0 = delta0 * x0;

    float hsn[DST];
    const float* Bp = Bws + p * DST;
    #pragma unroll
    for (int n = 0; n < DST; ++n) hsn[n] = coef0 * Bp[n];   // j=0 term, exp(0)=1

    if (L > 1) {
        float An[DST];
        #pragma unroll
        for (int n = 0; n < DST; ++n) An[n] = Aws[d * DST + n];
        float S = delta0;           // S_1 = delta at j=0
        int pj = p;
        for (int j = 1; j < L; ++j) {
            pj -= (WW + 1);         // step back along the diagonal
            float dj = dws[pj * DIN + d];
            float xj = xws[pj * DIN + d];
            float coef = dj * xj;
            const float* Bj = Bws + pj * DST;
            #pragma unroll
            for (int n = 0; n < DST; ++n) {
                float e = __expf(An[n] * S);
                hsn[n] = fmaf(e * Bj[n], coef, hsn[n]);
            }
            S += dj;
        }
    }

    const float* Cp = Cws + p * DST;
    float y = 0.0f;
    #pragma unroll
    for (int n = 0; n < DST; ++n) y = fmaf(hsn[n], Cp[n], y);
    y = fmaf(Dv[d], x0, y);
    out[i] = y;
}

extern "C" void kernel_launch(void* const* d_in, const int* in_sizes, int n_in,
                              void* d_out, int out_size, void* d_ws, size_t ws_size,
                              hipStream_t stream) {
    const float* x    = (const float*)d_in[0];
    const float* W1   = (const float*)d_in[1];
    const float* b1   = (const float*)d_in[2];
    const float* dtw  = (const float*)d_in[3];
    const float* dtb  = (const float*)d_in[4];
    const float* alog = (const float*)d_in[5];
    const float* Dv   = (const float*)d_in[6];
    float* out = (float*)d_out;

    char* ws = (char*)d_ws;
    float* dws = (float*)(ws);                    // NPIX*96 f32 = 12,582,912 B
    float* xws = (float*)(ws + 12582912);         // NPIX*96 f32
    float* Bws = (float*)(ws + 25165824);         // NPIX*16 f32 = 2,097,152 B
    float* Cws = (float*)(ws + 27262976);         // NPIX*16 f32
    float* Aws = (float*)(ws + 29360128);         // 96*16 f32

    hipLaunchKernelGGL(ssm2d_stage1, dim3(NPIX / 256), dim3(256), 0, stream,
                       x, W1, b1, dtw, dtb, alog, dws, xws, Bws, Cws, Aws);
    hipLaunchKernelGGL(ssm2d_stage2, dim3((NPIX * DIN) / 256), dim3(256), 0, stream,
                       dws, xws, Bws, Cws, Aws, Dv, out);
}

// Round 2
// 82.015 us; speedup vs baseline: 1.9420x; 1.9420x over previous
//
#include <hip/hip_runtime.h>
#include <cstdint>

#define CIN 96
#define DIN 96
#define DTR 8
#define DST 16
#define HH 128
#define WW 128
#define HW (HH*WW)
#define NPIX (2*HW)   // B=2
#define DIAG (WW+1)   // diagonal step back = 129

__device__ __forceinline__ float softplus_f(float t) {
    return (t > 20.0f) ? t : __logf(1.0f + __expf(t));
}

// ---------------- Stage 1: dBC matvec (40 outputs) + x transpose ----------------
// grid: NPIX/128 blocks of 512 threads. Wave g handles outputs [5g, 5g+5).
__global__ __launch_bounds__(512) void ssm2d_dbc(
    const float* __restrict__ x,
    const float* __restrict__ W1, const float* __restrict__ b1,
    float* __restrict__ dbc, float* __restrict__ xws)
{
    const int lane = threadIdx.x & 63;
    const int g = __builtin_amdgcn_readfirstlane(threadIdx.x >> 6); // 0..7, wave-uniform
    const int og = g * 5;
    const int p0 = blockIdx.x * 128;
    const int pA = p0 + lane;
    const int pB = p0 + 64 + lane;
    const int bb = p0 >> 14;                  // batch (block never straddles)
    const int qA = pA & (HW - 1);
    const int qB = pB & (HW - 1);
    const float* xb = x + (size_t)bb * CIN * HW;

    float accA[5], accB[5];
    #pragma unroll
    for (int o = 0; o < 5; ++o) { float bv = b1[og + o]; accA[o] = bv; accB[o] = bv; }

    #pragma unroll 4
    for (int ch = 0; ch < CIN; ch += 4) {
        float a0 = xb[(ch + 0) * HW + qA];
        float a1 = xb[(ch + 1) * HW + qA];
        float a2 = xb[(ch + 2) * HW + qA];
        float a3 = xb[(ch + 3) * HW + qA];
        float e0 = xb[(ch + 0) * HW + qB];
        float e1 = xb[(ch + 1) * HW + qB];
        float e2 = xb[(ch + 2) * HW + qB];
        float e3 = xb[(ch + 3) * HW + qB];
        if (g == 0) {   // one wave materializes the pixel-major transpose of x
            *reinterpret_cast<float4*>(xws + (size_t)pA * DIN + ch) = make_float4(a0, a1, a2, a3);
            *reinterpret_cast<float4*>(xws + (size_t)pB * DIN + ch) = make_float4(e0, e1, e2, e3);
        }
        #pragma unroll
        for (int o = 0; o < 5; ++o) {
            const float* wr = W1 + (og + o) * CIN + ch;   // wave-uniform -> s_load
            float w0 = wr[0], w1 = wr[1], w2 = wr[2], w3 = wr[3];
            accA[o] = fmaf(a0, w0, accA[o]);
            accA[o] = fmaf(a1, w1, accA[o]);
            accA[o] = fmaf(a2, w2, accA[o]);
            accA[o] = fmaf(a3, w3, accA[o]);
            accB[o] = fmaf(e0, w0, accB[o]);
            accB[o] = fmaf(e1, w1, accB[o]);
            accB[o] = fmaf(e2, w2, accB[o]);
            accB[o] = fmaf(e3, w3, accB[o]);
        }
    }
    #pragma unroll
    for (int o = 0; o < 5; ++o) {
        dbc[(size_t)pA * 40 + og + o] = accA[o];
        dbc[(size_t)pB * 40 + og + o] = accB[o];
    }
}

// ---------------- Stage 2: short chains (L <= 16), thread per (pixel, d) ----------------
__global__ __launch_bounds__(256) void ssm2d_scan(
    const float* __restrict__ dbc, const float* __restrict__ xws,
    const float* __restrict__ dtw, const float* __restrict__ dtb,
    const float* __restrict__ alog, const float* __restrict__ Dv,
    float* __restrict__ out)
{
    int i = blockIdx.x * 256 + threadIdx.x;   // i = p*96 + d
    int p = i / DIN;
    int d = i - p * DIN;
    int q = p & (HW - 1);
    int r = q >> 7;
    int c = q & (WW - 1);
    int m = __builtin_ctz(r + 1);
    int mc = __builtin_ctz(c + 1);
    if (mc < m) m = mc;
    if (m >= 5) return;                        // long chains -> stage 3
    int L = 1 << m;

    const float* rowd = dbc + (size_t)p * 40;
    float4 w0 = *reinterpret_cast<const float4*>(dtw + d * DTR);
    float4 w1 = *reinterpret_cast<const float4*>(dtw + d * DTR + 4);
    float tb = dtb[d];

    float4 k0 = *reinterpret_cast<const float4*>(rowd);
    float4 k1 = *reinterpret_cast<const float4*>(rowd + 4);
    float t = tb;
    t = fmaf(k0.x, w0.x, t); t = fmaf(k0.y, w0.y, t);
    t = fmaf(k0.z, w0.z, t); t = fmaf(k0.w, w0.w, t);
    t = fmaf(k1.x, w1.x, t); t = fmaf(k1.y, w1.y, t);
    t = fmaf(k1.z, w1.z, t); t = fmaf(k1.w, w1.w, t);
    float delta0 = softplus_f(t);
    float x0 = xws[i];
    float c0 = delta0 * x0;

    float hs[16];
    {
        float4 B0 = *reinterpret_cast<const float4*>(rowd + 8);
        float4 B1 = *reinterpret_cast<const float4*>(rowd + 12);
        float4 B2 = *reinterpret_cast<const float4*>(rowd + 16);
        float4 B3 = *reinterpret_cast<const float4*>(rowd + 20);
        hs[0]=c0*B0.x; hs[1]=c0*B0.y; hs[2]=c0*B0.z; hs[3]=c0*B0.w;
        hs[4]=c0*B1.x; hs[5]=c0*B1.y; hs[6]=c0*B1.z; hs[7]=c0*B1.w;
        hs[8]=c0*B2.x; hs[9]=c0*B2.y; hs[10]=c0*B2.z; hs[11]=c0*B2.w;
        hs[12]=c0*B3.x; hs[13]=c0*B3.y; hs[14]=c0*B3.z; hs[15]=c0*B3.w;
    }

    if (L > 1) {
        float An[16];
        const float* al = alog + d * DST;
        #pragma unroll
        for (int n = 0; n < 16; ++n) An[n] = -__expf(al[n]);
        float S = delta0;
        int pj = p;
        for (int j = 1; j < L; ++j) {
            pj -= DIAG;
            const float* rj = dbc + (size_t)pj * 40;
            float4 j0 = *reinterpret_cast<const float4*>(rj);
            float4 j1 = *reinterpret_cast<const float4*>(rj + 4);
            float tt = tb;
            tt = fmaf(j0.x, w0.x, tt); tt = fmaf(j0.y, w0.y, tt);
            tt = fmaf(j0.z, w0.z, tt); tt = fmaf(j0.w, w0.w, tt);
            tt = fmaf(j1.x, w1.x, tt); tt = fmaf(j1.y, w1.y, tt);
            tt = fmaf(j1.z, w1.z, tt); tt = fmaf(j1.w, w1.w, tt);
            float dj = softplus_f(tt);
            float xj = xws[(size_t)pj * DIN + d];
            float cj = dj * xj;
            float4 B0 = *reinterpret_cast<const float4*>(rj + 8);
            float4 B1 = *reinterpret_cast<const float4*>(rj + 12);
            float4 B2 = *reinterpret_cast<const float4*>(rj + 16);
            float4 B3 = *reinterpret_cast<const float4*>(rj + 20);
            float Bv[16] = {B0.x,B0.y,B0.z,B0.w, B1.x,B1.y,B1.z,B1.w,
                            B2.x,B2.y,B2.z,B2.w, B3.x,B3.y,B3.z,B3.w};
            #pragma unroll
            for (int n = 0; n < 16; ++n)
                hs[n] = fmaf(__expf(An[n] * S) * Bv[n], cj, hs[n]);
            S += dj;
        }
    }

    float4 C0 = *reinterpret_cast<const float4*>(rowd + 24);
    float4 C1 = *reinterpret_cast<const float4*>(rowd + 28);
    float4 C2 = *reinterpret_cast<const float4*>(rowd + 32);
    float4 C3 = *reinterpret_cast<const float4*>(rowd + 36);
    float y = 0.0f;
    y = fmaf(hs[0],C0.x,y); y = fmaf(hs[1],C0.y,y); y = fmaf(hs[2],C0.z,y); y = fmaf(hs[3],C0.w,y);
    y = fmaf(hs[4],C1.x,y); y = fmaf(hs[5],C1.y,y); y = fmaf(hs[6],C1.z,y); y = fmaf(hs[7],C1.w,y);
    y = fmaf(hs[8],C2.x,y); y = fmaf(hs[9],C2.y,y); y = fmaf(hs[10],C2.z,y); y = fmaf(hs[11],C2.w,y);
    y = fmaf(hs[12],C3.x,y); y = fmaf(hs[13],C3.y,y); y = fmaf(hs[14],C3.z,y); y = fmaf(hs[15],C3.w,y);
    y = fmaf(Dv[d], x0, y);
    out[i] = y;
}

// ---------------- Stage 3: long chains (L >= 32), one wave per (pixel, d), lane-parallel over j ----------------
__global__ __launch_bounds__(256) void ssm2d_scan_long(
    const float* __restrict__ dbc, const float* __restrict__ xws,
    const float* __restrict__ dtw, const float* __restrict__ dtb,
    const float* __restrict__ alog, const float* __restrict__ Dv,
    float* __restrict__ out)
{
    int wave = blockIdx.x * 4 + (threadIdx.x >> 6);   // 0..3071
    int lane = threadIdx.x & 63;
    int pix = wave / DIN;            // 0..31
    int d = wave - pix * DIN;
    int batch = pix >> 4;
    int sel = pix & 15;
    int r = ((sel >> 2) + 1) * 32 - 1;   // 31,63,95,127
    int c = ((sel & 3) + 1) * 32 - 1;
    int p = batch * HW + r * WW + c;
    int m = __builtin_ctz(r + 1);
    int mc = __builtin_ctz(c + 1);
    if (mc < m) m = mc;
    int L = 1 << m;                       // 32, 64, or 128

    float4 w0 = *reinterpret_cast<const float4*>(dtw + d * DTR);
    float4 w1 = *reinterpret_cast<const float4*>(dtw + d * DTR + 4);
    float tb = dtb[d];
    float An[16];
    #pragma unroll
    for (int n = 0; n < 16; ++n) An[n] = -__expf(alog[d * DST + n]);

    float acc[16];
    #pragma unroll
    for (int n = 0; n < 16; ++n) acc[n] = 0.0f;
    float Scarry = 0.0f;
    float x0 = 0.0f;

    for (int jb = 0; jb < L; jb += 64) {
        int j = jb + lane;
        bool act = (j < L);
        int jc = act ? j : 0;
        int pj = p - DIAG * jc;
        const float* rj = dbc + (size_t)pj * 40;
        float4 j0 = *reinterpret_cast<const float4*>(rj);
        float4 j1 = *reinterpret_cast<const float4*>(rj + 4);
        float tt = tb;
        tt = fmaf(j0.x, w0.x, tt); tt = fmaf(j0.y, w0.y, tt);
        tt = fmaf(j0.z, w0.z, tt); tt = fmaf(j0.w, w0.w, tt);
        tt = fmaf(j1.x, w1.x, tt); tt = fmaf(j1.y, w1.y, tt);
        tt = fmaf(j1.z, w1.z, tt); tt = fmaf(j1.w, w1.w, tt);
        float dj = softplus_f(tt);
        float xj = xws[(size_t)pj * DIN + d];
        if (!act) { dj = 0.0f; xj = 0.0f; }
        float cj = dj * xj;
        if (jb == 0) x0 = __shfl(xj, 0);

        // inclusive prefix-sum of dj over the wave
        float incl = dj;
        #pragma unroll
        for (int off = 1; off < 64; off <<= 1) {
            float v = __shfl_up(incl, off);
            if (lane >= off) incl += v;
        }
        float S = Scarry + incl - dj;     // exclusive prefix + carry

        float4 B0 = *reinterpret_cast<const float4*>(rj + 8);
        float4 B1 = *reinterpret_cast<const float4*>(rj + 12);
        float4 B2 = *reinterpret_cast<const float4*>(rj + 16);
        float4 B3 = *reinterpret_cast<const float4*>(rj + 20);
        float Bv[16] = {B0.x,B0.y,B0.z,B0.w, B1.x,B1.y,B1.z,B1.w,
                        B2.x,B2.y,B2.z,B2.w, B3.x,B3.y,B3.z,B3.w};
        #pragma unroll
        for (int n = 0; n < 16; ++n)
            acc[n] = fmaf(__expf(An[n] * S) * Bv[n], cj, acc[n]);

        Scarry += __shfl(incl, 63);
    }

    // butterfly reduce the 16 accumulators across the wave
    #pragma unroll
    for (int off = 32; off >= 1; off >>= 1) {
        #pragma unroll
        for (int n = 0; n < 16; ++n) acc[n] += __shfl_xor(acc[n], off);
    }

    if (lane == 0) {
        const float* rowd = dbc + (size_t)p * 40;
        float4 C0 = *reinterpret_cast<const float4*>(rowd + 24);
        float4 C1 = *reinterpret_cast<const float4*>(rowd + 28);
        float4 C2 = *reinterpret_cast<const float4*>(rowd + 32);
        float4 C3 = *reinterpret_cast<const float4*>(rowd + 36);
        float y = 0.0f;
        y = fmaf(acc[0],C0.x,y); y = fmaf(acc[1],C0.y,y); y = fmaf(acc[2],C0.z,y); y = fmaf(acc[3],C0.w,y);
        y = fmaf(acc[4],C1.x,y); y = fmaf(acc[5],C1.y,y); y = fmaf(acc[6],C1.z,y); y = fmaf(acc[7],C1.w,y);
        y = fmaf(acc[8],C2.x,y); y = fmaf(acc[9],C2.y,y); y = fmaf(acc[10],C2.z,y); y = fmaf(acc[11],C2.w,y);
        y = fmaf(acc[12],C3.x,y); y = fmaf(acc[13],C3.y,y); y = fmaf(acc[14],C3.z,y); y = fmaf(acc[15],C3.w,y);
        y = fmaf(Dv[d], x0, y);
        out[(size_t)p * DIN + d] = y;
    }
}

extern "C" void kernel_launch(void* const* d_in, const int* in_sizes, int n_in,
                              void* d_out, int out_size, void* d_ws, size_t ws_size,
                              hipStream_t stream) {
    const float* x    = (const float*)d_in[0];
    const float* W1   = (const float*)d_in[1];
    const float* b1   = (const float*)d_in[2];
    const float* dtw  = (const float*)d_in[3];
    const float* dtb  = (const float*)d_in[4];
    const float* alog = (const float*)d_in[5];
    const float* Dv   = (const float*)d_in[6];
    float* out = (float*)d_out;

    char* ws = (char*)d_ws;
    float* dbc = (float*)(ws);                 // NPIX*40 f32 = 5,242,880 B
    float* xws = (float*)(ws + 5242880);       // NPIX*96 f32 = 12,582,912 B

    hipLaunchKernelGGL(ssm2d_dbc, dim3(NPIX / 128), dim3(512), 0, stream,
                       x, W1, b1, dbc, xws);
    hipLaunchKernelGGL(ssm2d_scan_long, dim3(768), dim3(256), 0, stream,
                       dbc, xws, dtw, dtb, alog, Dv, out);
    hipLaunchKernelGGL(ssm2d_scan, dim3((NPIX * DIN) / 256), dim3(256), 0, stream,
                       dbc, xws, dtw, dtb, alog, Dv, out);
}